// Round 9
// baseline (22237.247 us; speedup 1.0000x reference)
//
#include <hip/hip_runtime.h>
#include <stdint.h>

#define T_TOK 4096
#define HDIM 2048
#define MDIM 1408
#define NEXP 28
#define TOPK 6
#define NPAIR (T_TOK*TOPK)   // 24576

typedef unsigned short u16;
typedef short short8 __attribute__((ext_vector_type(8)));
typedef float f32x4 __attribute__((ext_vector_type(4)));

__device__ __forceinline__ u16 f2bf(float x){
  unsigned int u = __float_as_uint(x);
  u += 0x7fffu + ((u >> 16) & 1u);
  return (u16)(u >> 16);
}
__device__ __forceinline__ float bf2f(unsigned int h){
  return __uint_as_float(h << 16);
}
__device__ __forceinline__ unsigned cvtpk(float a, float b){
  unsigned r; asm("v_cvt_pk_bf16_f32 %0, %1, %2" : "=v"(r) : "v"(a), "v"(b)); return r;
}

__device__ __forceinline__ void gload16(const u16* g, u16* l){
  __builtin_amdgcn_global_load_lds((const __attribute__((address_space(1))) unsigned int*)g,
                                   (__attribute__((address_space(3))) unsigned int*)l,
                                   16, 0, 0);
}

#define BAR_FENCE asm volatile("s_barrier" ::: "memory")
#define SB0 __builtin_amdgcn_sched_barrier(0)

// ---------------- x fp32 -> bf16 ----------------
__global__ __launch_bounds__(256) void cvt_kernel(const float* __restrict__ x,
                                                  u16* __restrict__ xb, int n8){
  int i = blockIdx.x*256 + threadIdx.x;
  if (i >= n8) return;
  const float4* s = (const float4*)x + (size_t)i*2;
  float4 a = s[0], b = s[1];
  unsigned int w0 = (unsigned)f2bf(a.x) | ((unsigned)f2bf(a.y)<<16);
  unsigned int w1 = (unsigned)f2bf(a.z) | ((unsigned)f2bf(a.w)<<16);
  unsigned int w2 = (unsigned)f2bf(b.x) | ((unsigned)f2bf(b.y)<<16);
  unsigned int w3 = (unsigned)f2bf(b.z) | ((unsigned)f2bf(b.w)<<16);
  uint4 o = {w0,w1,w2,w3};
  ((uint4*)xb)[i] = o;
}

// ---------------- gating ----------------
__global__ __launch_bounds__(256) void gate_kernel(const float* __restrict__ x,
                                                   const float* __restrict__ gw,
                                                   int* __restrict__ topk_idx,
                                                   float* __restrict__ topk_w,
                                                   int* __restrict__ counts){
  const int wave = threadIdx.x >> 6, lane = threadIdx.x & 63;
  const int t = blockIdx.x*4 + wave;
  const float* xr = x + (size_t)t*HDIM;
  float xv[32];
  #pragma unroll
  for (int i=0;i<32;i++) xv[i] = xr[lane + 64*i];
  float sc[NEXP];
  #pragma unroll
  for (int e=0;e<NEXP;e++){
    const float* g = gw + (size_t)e*HDIM + lane;
    float a = 0.f;
    #pragma unroll
    for (int i=0;i<32;i++) a += xv[i]*g[64*i];
    #pragma unroll
    for (int d=32; d>0; d>>=1) a += __shfl_xor(a, d);
    sc[e] = a;
  }
  float mx = sc[0];
  #pragma unroll
  for (int e=1;e<NEXP;e++) mx = fmaxf(mx, sc[e]);
  unsigned int mask=0; int bi[TOPK]; float bs[TOPK]; float bsum=0.f;
  #pragma unroll
  for (int k=0;k<TOPK;k++){
    float bm=-3.4e38f; int bj=0;
    #pragma unroll
    for (int e=0;e<NEXP;e++){
      bool ok = (((mask>>e)&1u)==0u) && (sc[e]>bm);
      bm = ok ? sc[e] : bm; bj = ok ? e : bj;
    }
    mask |= (1u<<bj);
    float s = expf(bm - mx);
    bi[k]=bj; bs[k]=s; bsum+=s;
  }
  if (lane==0){
    float inv = 1.f/(bsum + 1e-20f);
    #pragma unroll
    for (int k=0;k<TOPK;k++){
      topk_idx[t*TOPK+k]=bi[k];
      topk_w[t*TOPK+k]=bs[k]*inv;
      atomicAdd(&counts[bi[k]],1);
    }
  }
}

__global__ void scan_kernel(const int* __restrict__ counts, int* __restrict__ offsets,
                            int* __restrict__ cursor){
  int t = threadIdx.x;
  if (t < NEXP) cursor[t] = 0;
  if (t == 0){
    int s = 0;
    for (int e=0;e<NEXP;e++){ offsets[e]=s; s+=counts[e]; }
    offsets[NEXP]=s;
  }
}

__global__ __launch_bounds__(256) void fill_kernel(const int* __restrict__ topk_idx,
                                                   const float* __restrict__ topk_w,
                                                   const int* __restrict__ offsets,
                                                   int* __restrict__ cursor,
                                                   int* __restrict__ pair_token,
                                                   int* __restrict__ pos){
  int t = blockIdx.x*256 + threadIdx.x;
  if (t >= T_TOK) return;
  #pragma unroll
  for (int k=0;k<TOPK;k++){
    int e = topk_idx[t*TOPK+k];
    int c = atomicAdd(&cursor[e],1);
    int p = offsets[e]+c;
    pair_token[p]=t;
    pos[t*TOPK+k]=p;
  }
}

// ---------------- grouped GEMM: BM=256, BN=128, BK=64, 512 thr (4Mx2N waves) ----------------
// B is fp32 [E][K][N] read DIRECTLY (no transpose pass): per thread 16 k-strided dwords
// (coalesced across lanes) -> v_cvt_pk_bf16_f32 -> 2x ds_write_b128 into the swizzled
// [n][k] layout the frag reads use. 3-stage pipeline: B loads(t+2) issue at iter t,
// cvt+write at iter t+1, consumed at t+2 — every wait has >=1 full iteration of cover.
// A rows bf16 via global_load_lds (2-deep, counted vmcnt retires exactly A(t+1)).
template<int NB, bool GATHER, int EPI, int NBN>
__global__ __launch_bounds__(512,1) void gemm9(
    const u16* __restrict__ Ab, const float* __restrict__ B0f, const float* __restrict__ B1f,
    u16* __restrict__ Hout,
    const int* __restrict__ counts, const int* __restrict__ offsets,
    const int* __restrict__ pair_token,
    int K, int N, int cpx)
{
  extern __shared__ u16 smem[];
  constexpr int BUFSZ = (NB==2) ? 32768 : 24576;   // u16: A 16K | B0 8K | (B1 8K)

  const int bid = blockIdx.x;
  const int swz = (bid & 7)*cpx + (bid >> 3);
  const int rb  = swz & 7;
  const int rest = swz >> 3;
  const int n0b = rest % NBN;
  const int e   = rest / NBN;

  const int cnt = counts[e];
  const int row0 = rb*256;
  if (row0 >= cnt) return;
  const int off = offsets[e];
  const int n0 = n0b*128;

  const int tid = threadIdx.x;
  const int lane = tid&63, wid = tid>>6;
  const int wm = wid>>1, wn = wid&1;     // 4M x 2N, per-wave 64x64
  const int lrow = lane&15, lgrp = lane>>4;

  // A staging sources (chunk swizzle baked into global source)
  const u16* ap[4];
  #pragma unroll
  for (int i=0;i<4;i++){
    int c = tid + 512*i;
    int r = c>>3;
    int u = (c&7) ^ (r&7);
    int pr = off + min(row0 + r, cnt-1);
    const u16* arow = GATHER ? (Ab + (size_t)pair_token[pr]*K) : (Ab + (size_t)pr*K);
    ap[i] = arow + u*8;
  }

  // B fp32 staging: thread covers (n = tid&127, k = bkg*16 .. +16)
  const int bn = tid & 127;
  const int bkg = tid >> 7;              // 0..3
  const float* b0p = B0f + (size_t)e*K*N + (size_t)(bkg*16)*N + (n0 + bn);
  const float* b1p = (NB==2) ? (B1f + (size_t)e*K*N + (size_t)(bkg*16)*N + (n0 + bn)) : nullptr;
  // LDS write offsets (u16 units, relative to B region base): row bn, chunks 2bkg, 2bkg+1 swizzled
  const int bw0 = bn*64 + ((2*bkg  )^(bn&7))*8;
  const int bw1 = bn*64 + ((2*bkg+1)^(bn&7))*8;

  // fragment LDS addressing (row&7 == lrow&7 for all frags)
  const int sA0 = ((lgrp)   ^ (lrow&7))*8;
  const int sA1 = ((4+lgrp) ^ (lrow&7))*8;
  const int abase = (wm*64 + lrow)*64;
  const int bbase = 16384 + (wn*64 + lrow)*64;

  f32x4 acc0[4][4] = {};
  f32x4 acc1[4][4] = {};
  float b0r[16], b1r[16];

  const int nt = K/64;

  // ---- prologue ----
  // issue B(0) + A(0)->buf0
  #pragma unroll
  for (int i=0;i<16;i++) b0r[i] = b0p[(size_t)i*N];
  if (NB==2){
    #pragma unroll
    for (int i=0;i<16;i++) b1r[i] = b1p[(size_t)i*N];
  }
  #pragma unroll
  for (int i=0;i<4;i++) gload16(ap[i], &smem[(tid+512*i)*8]);
  // cvt+write B(0) -> buf0 (compiler inserts the vmcnt wait for b0r/b1r)
  {
    uint4 w0, w1;
    w0.x=cvtpk(b0r[0],b0r[1]); w0.y=cvtpk(b0r[2],b0r[3]); w0.z=cvtpk(b0r[4],b0r[5]); w0.w=cvtpk(b0r[6],b0r[7]);
    w1.x=cvtpk(b0r[8],b0r[9]); w1.y=cvtpk(b0r[10],b0r[11]); w1.z=cvtpk(b0r[12],b0r[13]); w1.w=cvtpk(b0r[14],b0r[15]);
    *(uint4*)&smem[16384 + bw0] = w0;
    *(uint4*)&smem[16384 + bw1] = w1;
    if (NB==2){
      uint4 v0, v1;
      v0.x=cvtpk(b1r[0],b1r[1]); v0.y=cvtpk(b1r[2],b1r[3]); v0.z=cvtpk(b1r[4],b1r[5]); v0.w=cvtpk(b1r[6],b1r[7]);
      v1.x=cvtpk(b1r[8],b1r[9]); v1.y=cvtpk(b1r[10],b1r[11]); v1.z=cvtpk(b1r[12],b1r[13]); v1.w=cvtpk(b1r[14],b1r[15]);
      *(uint4*)&smem[24576 + bw0] = v0;
      *(uint4*)&smem[24576 + bw1] = v1;
    }
  }
  // issue B(1) + A(1)->buf1
  #pragma unroll
  for (int i=0;i<16;i++) b0r[i] = b0p[(size_t)(64+i)*N];
  if (NB==2){
    #pragma unroll
    for (int i=0;i<16;i++) b1r[i] = b1p[(size_t)(64+i)*N];
  }
  #pragma unroll
  for (int i=0;i<4;i++) gload16(ap[i]+64, &smem[BUFSZ + (tid+512*i)*8]);
  SB0;
  // retire A(0) exactly: outstanding = A(0)[4] + B(1)[32|16] + A(1)[4]
  if (NB==2) asm volatile("s_waitcnt vmcnt(36)" ::: "memory");
  else       asm volatile("s_waitcnt vmcnt(20)" ::: "memory");
  asm volatile("s_waitcnt lgkmcnt(0)" ::: "memory");
  BAR_FENCE;

  for (int t=0; t<nt; ++t){
    const u16* sc = smem + (t&1)*BUFSZ;
    u16* so = smem + ((t+1)&1)*BUFSZ;   // B(t+1) write target
    u16* sn = smem + (t&1)*BUFSZ;       // A(t+2) target (freed below)

    __builtin_amdgcn_s_setprio(1);
    // frag reads (current tile)
    short8 af[2][4], b0f[2][4], b1f[2][4];
    #pragma unroll
    for (int kh=0;kh<2;kh++){
      const int sk = kh ? sA1 : sA0;
      #pragma unroll
      for (int fm=0;fm<4;fm++) af[kh][fm] = *(const short8*)&sc[abase + fm*1024 + sk];
      #pragma unroll
      for (int fn=0;fn<4;fn++){
        b0f[kh][fn] = *(const short8*)&sc[bbase + fn*1024 + sk];
        if (NB==2) b1f[kh][fn] = *(const short8*)&sc[8192 + bbase + fn*1024 + sk];
      }
    }
    // cvt+write B(t+1) into the other buffer (loads issued one iter ago)
    if (t+1 < nt){
      uint4 w0, w1;
      w0.x=cvtpk(b0r[0],b0r[1]); w0.y=cvtpk(b0r[2],b0r[3]); w0.z=cvtpk(b0r[4],b0r[5]); w0.w=cvtpk(b0r[6],b0r[7]);
      w1.x=cvtpk(b0r[8],b0r[9]); w1.y=cvtpk(b0r[10],b0r[11]); w1.z=cvtpk(b0r[12],b0r[13]); w1.w=cvtpk(b0r[14],b0r[15]);
      *(uint4*)&so[16384 + bw0] = w0;
      *(uint4*)&so[16384 + bw1] = w1;
      if (NB==2){
        uint4 v0, v1;
        v0.x=cvtpk(b1r[0],b1r[1]); v0.y=cvtpk(b1r[2],b1r[3]); v0.z=cvtpk(b1r[4],b1r[5]); v0.w=cvtpk(b1r[6],b1r[7]);
        v1.x=cvtpk(b1r[8],b1r[9]); v1.y=cvtpk(b1r[10],b1r[11]); v1.z=cvtpk(b1r[12],b1r[13]); v1.w=cvtpk(b1r[14],b1r[15]);
        *(uint4*)&so[24576 + bw0] = v0;
        *(uint4*)&so[24576 + bw1] = v1;
      }
    }
    // MFMAs
    #pragma unroll
    for (int kh=0;kh<2;kh++){
      #pragma unroll
      for (int fm=0;fm<4;fm++){
        #pragma unroll
        for (int fn=0;fn<4;fn++){
          acc0[fm][fn] = __builtin_amdgcn_mfma_f32_16x16x32_bf16(af[kh][fm], b0f[kh][fn], acc0[fm][fn],0,0,0);
          if (NB==2)
            acc1[fm][fn] = __builtin_amdgcn_mfma_f32_16x16x32_bf16(af[kh][fm], b1f[kh][fn], acc1[fm][fn],0,0,0);
        }
      }
    }
    __builtin_amdgcn_s_setprio(0);

    // drain own LDS ops (frag reads + B writes), then buffer-handoff barrier
    asm volatile("s_waitcnt lgkmcnt(0)" ::: "memory");
    BAR_FENCE;

    if (t+2 < nt){
      const size_t kt2 = (size_t)(t+2)*64;
      // issue B(t+2) -> regs
      #pragma unroll
      for (int i=0;i<16;i++) b0r[i] = b0p[(kt2+i)*N];
      if (NB==2){
        #pragma unroll
        for (int i=0;i<16;i++) b1r[i] = b1p[(kt2+i)*N];
      }
      // issue A(t+2) -> just-freed buffer
      #pragma unroll
      for (int i=0;i<4;i++) gload16(ap[i] + kt2, &sn[(tid+512*i)*8]);
      SB0;
      // retire A(t+1) exactly; B(t+2)+A(t+2) stay in flight
      if (NB==2) asm volatile("s_waitcnt vmcnt(36)" ::: "memory");
      else       asm volatile("s_waitcnt vmcnt(20)" ::: "memory");
    } else if (t+1 < nt){
      asm volatile("s_waitcnt vmcnt(0)" ::: "memory");
    }
    if (t+1 < nt) BAR_FENCE;
  }

  // epilogue
  #pragma unroll
  for (int fm=0;fm<4;fm++){
    #pragma unroll
    for (int j=0;j<4;j++){
      int grow = wm*64 + fm*16 + lgrp*4 + j;
      if (row0+grow < cnt){
        int p = off + row0 + grow;
        u16* hrow = Hout + (size_t)p*N;
        #pragma unroll
        for (int fn=0;fn<4;fn++){
          int col = n0 + wn*64 + fn*16 + lrow;
          if (EPI==0){
            float g = acc0[fm][fn][j], u = acc1[fm][fn][j];
            hrow[col] = f2bf(g*u/(1.f+expf(-g)));
          } else {
            hrow[col] = f2bf(acc0[fm][fn][j]);
          }
        }
      }
    }
  }
}

// ---------------- combine ----------------
__global__ __launch_bounds__(256) void combine_kernel(const u16* __restrict__ pairbuf,
                                                      const int* __restrict__ pos,
                                                      const float* __restrict__ topk_w,
                                                      float* __restrict__ out){
  const int t = blockIdx.x;
  const int c = threadIdx.x*8;
  float acc[8] = {};
  #pragma unroll
  for (int k=0;k<TOPK;k++){
    int p = pos[t*TOPK+k];
    float w = topk_w[t*TOPK+k];
    uint4 v = *(const uint4*)&pairbuf[(size_t)p*HDIM + c];
    unsigned int ws_[4] = {v.x,v.y,v.z,v.w};
    #pragma unroll
    for (int j=0;j<4;j++){
      acc[2*j]   += w*bf2f(ws_[j]&0xffffu);
      acc[2*j+1] += w*bf2f(ws_[j]>>16);
    }
  }
  float4 o0 = {acc[0],acc[1],acc[2],acc[3]};
  float4 o1 = {acc[4],acc[5],acc[6],acc[7]};
  float* orow = out + (size_t)t*HDIM + c;
  *(float4*)orow = o0;
  *(float4*)(orow+4) = o1;
}

extern "C" void kernel_launch(void* const* d_in, const int* in_sizes, int n_in,
                              void* d_out, int out_size, void* d_ws, size_t ws_size,
                              hipStream_t stream) {
  const float* x  = (const float*)d_in[0];
  const float* gw = (const float*)d_in[1];
  const float* wg = (const float*)d_in[2];
  const float* wu = (const float*)d_in[3];
  const float* wd = (const float*)d_in[4];
  float* out = (float*)d_out;

  char* p = (char*)d_ws;
  u16* xb      = (u16*)p; p += (size_t)T_TOK*HDIM*2;   // 16.8 MB
  u16* hbuf    = (u16*)p; p += (size_t)NPAIR*MDIM*2;   // 69.2 MB
  u16* pairbuf = (u16*)p; p += (size_t)NPAIR*HDIM*2;   // 100.7 MB
  int*   topk_idx   = (int*)p;   p += NPAIR*4;
  float* topk_w     = (float*)p; p += NPAIR*4;
  int*   pair_token = (int*)p;   p += NPAIR*4;
  int*   pos        = (int*)p;   p += NPAIR*4;
  int*   counts     = (int*)p;   p += 128;
  int*   offsets    = (int*)p;   p += 128;
  int*   cursor     = (int*)p;   p += 128;

  hipMemsetAsync(counts, 0, 128, stream);
  cvt_kernel<<<T_TOK*HDIM/8/256, 256, 0, stream>>>(x, xb, T_TOK*HDIM/8);
  gate_kernel<<<T_TOK/4, 256, 0, stream>>>(x, gw, topk_idx, topk_w, counts);
  scan_kernel<<<1, 64, 0, stream>>>(counts, offsets, cursor);
  fill_kernel<<<T_TOK/256, 256, 0, stream>>>(topk_idx, topk_w, offsets, cursor, pair_token, pos);

  // stage 1: h = silu(x@wg) * (x@wu) — B = fp32 weights read directly
  {
    int ntile = 8*(MDIM/128)*NEXP;   // 2464
    gemm9<2,true,0,(MDIM/128)><<<ntile, 512, 131072, stream>>>(
        xb, wg, wu, hbuf, counts, offsets, pair_token, HDIM, MDIM, ntile/8);
  }

  // stage 2: pairbuf = h @ wd — B = fp32 wd read directly
  {
    int ntile = 8*(HDIM/128)*NEXP;   // 3584
    gemm9<1,false,1,(HDIM/128)><<<ntile, 512, 98304, stream>>>(
        hbuf, wd, nullptr, pairbuf, counts, offsets, pair_token, MDIM, HDIM, ntile/8);
  }

  combine_kernel<<<T_TOK, 256, 0, stream>>>(pairbuf, pos, topk_w, out);
}

// Round 10
// 1443.762 us; speedup vs baseline: 15.4023x; 15.4023x over previous
//
#include <hip/hip_runtime.h>
#include <stdint.h>

#define T_TOK 4096
#define HDIM 2048
#define MDIM 1408
#define NEXP 28
#define TOPK 6
#define NPAIR (T_TOK*TOPK)   // 24576

typedef unsigned short u16;
typedef short short8 __attribute__((ext_vector_type(8)));
typedef float f32x4 __attribute__((ext_vector_type(4)));

__device__ __forceinline__ u16 f2bf(float x){
  unsigned int u = __float_as_uint(x);
  u += 0x7fffu + ((u >> 16) & 1u);
  return (u16)(u >> 16);
}
__device__ __forceinline__ float bf2f(unsigned int h){
  return __uint_as_float(h << 16);
}
__device__ __forceinline__ unsigned cvtpk(float a, float b){
  unsigned r; asm("v_cvt_pk_bf16_f32 %0, %1, %2" : "=v"(r) : "v"(a), "v"(b)); return r;
}

__device__ __forceinline__ void gload16(const u16* g, u16* l){
  __builtin_amdgcn_global_load_lds((const __attribute__((address_space(1))) unsigned int*)g,
                                   (__attribute__((address_space(3))) unsigned int*)l,
                                   16, 0, 0);
}

#define BAR_FENCE asm volatile("s_barrier" ::: "memory")
#define SB0 __builtin_amdgcn_sched_barrier(0)

// ---------------- x fp32 -> bf16 ----------------
__global__ __launch_bounds__(256) void cvt_kernel(const float* __restrict__ x,
                                                  u16* __restrict__ xb, int n8){
  int i = blockIdx.x*256 + threadIdx.x;
  if (i >= n8) return;
  const float4* s = (const float4*)x + (size_t)i*2;
  float4 a = s[0], b = s[1];
  unsigned int w0 = (unsigned)f2bf(a.x) | ((unsigned)f2bf(a.y)<<16);
  unsigned int w1 = (unsigned)f2bf(a.z) | ((unsigned)f2bf(a.w)<<16);
  unsigned int w2 = (unsigned)f2bf(b.x) | ((unsigned)f2bf(b.y)<<16);
  unsigned int w3 = (unsigned)f2bf(b.z) | ((unsigned)f2bf(b.w)<<16);
  uint4 o = {w0,w1,w2,w3};
  ((uint4*)xb)[i] = o;
}

// ---------------- gating ----------------
__global__ __launch_bounds__(256) void gate_kernel(const float* __restrict__ x,
                                                   const float* __restrict__ gw,
                                                   int* __restrict__ topk_idx,
                                                   float* __restrict__ topk_w,
                                                   int* __restrict__ counts){
  const int wave = threadIdx.x >> 6, lane = threadIdx.x & 63;
  const int t = blockIdx.x*4 + wave;
  const float* xr = x + (size_t)t*HDIM;
  float xv[32];
  #pragma unroll
  for (int i=0;i<32;i++) xv[i] = xr[lane + 64*i];
  float sc[NEXP];
  #pragma unroll
  for (int e=0;e<NEXP;e++){
    const float* g = gw + (size_t)e*HDIM + lane;
    float a = 0.f;
    #pragma unroll
    for (int i=0;i<32;i++) a += xv[i]*g[64*i];
    #pragma unroll
    for (int d=32; d>0; d>>=1) a += __shfl_xor(a, d);
    sc[e] = a;
  }
  float mx = sc[0];
  #pragma unroll
  for (int e=1;e<NEXP;e++) mx = fmaxf(mx, sc[e]);
  unsigned int mask=0; int bi[TOPK]; float bs[TOPK]; float bsum=0.f;
  #pragma unroll
  for (int k=0;k<TOPK;k++){
    float bm=-3.4e38f; int bj=0;
    #pragma unroll
    for (int e=0;e<NEXP;e++){
      bool ok = (((mask>>e)&1u)==0u) && (sc[e]>bm);
      bm = ok ? sc[e] : bm; bj = ok ? e : bj;
    }
    mask |= (1u<<bj);
    float s = expf(bm - mx);
    bi[k]=bj; bs[k]=s; bsum+=s;
  }
  if (lane==0){
    float inv = 1.f/(bsum + 1e-20f);
    #pragma unroll
    for (int k=0;k<TOPK;k++){
      topk_idx[t*TOPK+k]=bi[k];
      topk_w[t*TOPK+k]=bs[k]*inv;
      atomicAdd(&counts[bi[k]],1);
    }
  }
}

__global__ void scan_kernel(const int* __restrict__ counts, int* __restrict__ offsets,
                            int* __restrict__ cursor){
  int t = threadIdx.x;
  if (t < NEXP) cursor[t] = 0;
  if (t == 0){
    int s = 0;
    for (int e=0;e<NEXP;e++){ offsets[e]=s; s+=counts[e]; }
    offsets[NEXP]=s;
  }
}

__global__ __launch_bounds__(256) void fill_kernel(const int* __restrict__ topk_idx,
                                                   const float* __restrict__ topk_w,
                                                   const int* __restrict__ offsets,
                                                   int* __restrict__ cursor,
                                                   int* __restrict__ pair_token,
                                                   int* __restrict__ pos){
  int t = blockIdx.x*256 + threadIdx.x;
  if (t >= T_TOK) return;
  #pragma unroll
  for (int k=0;k<TOPK;k++){
    int e = topk_idx[t*TOPK+k];
    int c = atomicAdd(&cursor[e],1);
    int p = offsets[e]+c;
    pair_token[p]=t;
    pos[t*TOPK+k]=p;
  }
}

// ---------------- grouped GEMM, producer/consumer waves ----------------
// Block = 768 thr: waves 0-7 compute (BM=256,BN=128,BK=64, 4Mx2N, A via global_load_lds,
// 2-deep counted vmcnt(4)); waves 8-11 producers (B fp32 -> cvt_pk -> swizzled ds_write,
// 3-stage: load B(t+2) issued one full iteration before its cvt+write at t+1, consumed t+2).
// Staged fp32 regs live only in producer waves (no accumulators there) -> no spills.
// Barriers: 1 prologue + 2 per iter on BOTH paths.
template<int NB, bool GATHER, int EPI, int NBN>
__global__ __launch_bounds__(768,1) void gemm10(
    const u16* __restrict__ Ab, const float* __restrict__ B0f, const float* __restrict__ B1f,
    u16* __restrict__ Hout,
    const int* __restrict__ counts, const int* __restrict__ offsets,
    const int* __restrict__ pair_token,
    int K, int N, int cpx)
{
  extern __shared__ u16 smem[];
  constexpr int BUFSZ = (NB==2) ? 32768 : 24576;   // u16: A 16K | B0 8K | (B1 8K)

  const int bid = blockIdx.x;
  const int swz = (bid & 7)*cpx + (bid >> 3);
  const int rb  = swz & 7;
  const int rest = swz >> 3;
  const int n0b = rest % NBN;
  const int e   = rest / NBN;

  const int cnt = counts[e];
  const int row0 = rb*256;
  if (row0 >= cnt) return;
  const int off = offsets[e];
  const int n0 = n0b*128;

  const int tid = threadIdx.x;
  const int nt = K/64;

  if (tid >= 512){
    // ================= producer waves =================
    const int p = tid - 512;                   // 0..255
    const int q = p & 31;
    const int nloc = 4*q;
    constexpr int NK = (NB==2) ? 16 : 8;       // k-values per thread per tile
    const int m = (NB==2) ? (p>>7) : 0;
    const int kslot = (NB==2) ? ((p>>5)&3) : (p>>5);
    const float* bsrc = ((NB==2) && m) ? B1f : B0f;
    const float* bp = bsrc + (size_t)e*K*N + (size_t)(kslot*NK)*N + (n0 + nloc);
    const int matbase = 16384 + (((NB==2) && m) ? 8192 : 0);

    f32x4 st[NK];
    auto LOADT = [&](int kt){
      #pragma unroll
      for (int j=0;j<NK;j++) st[j] = *(const f32x4*)&bp[((size_t)kt + j)*N];
    };
    auto WRITET = [&](int bb){
      #pragma unroll
      for (int i=0;i<4;i++){
        int n = nloc + i;
        if constexpr (NB==2){
          int o0 = bb + matbase + n*64 + ((2*kslot  )^(n&7))*8;
          int o1 = bb + matbase + n*64 + ((2*kslot+1)^(n&7))*8;
          uint4 w0 = { cvtpk(st[0][i],st[1][i]),  cvtpk(st[2][i],st[3][i]),
                       cvtpk(st[4][i],st[5][i]),  cvtpk(st[6][i],st[7][i]) };
          uint4 w1 = { cvtpk(st[8][i],st[9][i]),  cvtpk(st[10][i],st[11][i]),
                       cvtpk(st[12][i],st[13][i]),cvtpk(st[14][i],st[15][i]) };
          *(uint4*)&smem[o0] = w0;
          *(uint4*)&smem[o1] = w1;
        } else {
          int o0 = bb + matbase + n*64 + ((kslot)^(n&7))*8;
          uint4 w0 = { cvtpk(st[0][i],st[1][i]), cvtpk(st[2][i],st[3][i]),
                       cvtpk(st[4][i],st[5][i]), cvtpk(st[6][i],st[7][i]) };
          *(uint4*)&smem[o0] = w0;
        }
      }
    };

    // prologue: B(0) -> buf0; B(1) -> regs
    LOADT(0);
    WRITET(0);
    LOADT(64);
    asm volatile("s_waitcnt lgkmcnt(0)" ::: "memory");
    BAR_FENCE;                                  // joint prologue barrier

    for (int t=0; t<nt; ++t){
      if (t+1 < nt) WRITET(((t+1)&1)*BUFSZ);    // cvt+write B(t+1) (regs loaded 1 iter ago)
      asm volatile("s_waitcnt lgkmcnt(0)" ::: "memory");
      BAR_FENCE;                                // BAR1
      if (t+2 < nt) LOADT((t+2)*64);            // issue B(t+2) -> regs
      SB0;
      BAR_FENCE;                                // BAR2
    }
    return;
  }

  // ================= compute waves =================
  const int lane = tid&63, wid = tid>>6;
  const int wm = wid>>1, wn = wid&1;            // 4M x 2N, per-wave 64x64
  const int lrow = lane&15, lgrp = lane>>4;

  const u16* ap[4];
  #pragma unroll
  for (int i=0;i<4;i++){
    int c = tid + 512*i;                        // A: 2048 chunks, r in [0,256)
    int r = c>>3;
    int u = (c&7) ^ (r&7);
    int pr = off + min(row0 + r, cnt-1);
    const u16* arow = GATHER ? (Ab + (size_t)pair_token[pr]*K) : (Ab + (size_t)pr*K);
    ap[i] = arow + u*8;
  }

  const int sA0 = ((lgrp)   ^ (lrow&7))*8;
  const int sA1 = ((4+lgrp) ^ (lrow&7))*8;
  const int abase = (wm*64 + lrow)*64;
  const int bbase = 16384 + (wn*64 + lrow)*64;

  f32x4 acc0[4][4] = {};
  f32x4 acc1[4][4] = {};

  // prologue: A(0)->buf0, A(1)->buf1
  #pragma unroll
  for (int i=0;i<4;i++) gload16(ap[i], &smem[(tid+512*i)*8]);
  #pragma unroll
  for (int i=0;i<4;i++) gload16(ap[i]+64, &smem[BUFSZ + (tid+512*i)*8]);
  asm volatile("s_waitcnt vmcnt(4)" ::: "memory");   // retire A(0); A(1) in flight
  BAR_FENCE;                                   // joint prologue barrier

  for (int t=0; t<nt; ++t){
    const u16* sc = smem + (t&1)*BUFSZ;
    u16* sn = (u16*)sc;                        // A(t+2) reuses cur A region

    // reads + MFMAs in one region (compiler interleaves with fine-grained lgkmcnt)
    short8 af[2][4], b0f[2][4], b1f[2][4];
    __builtin_amdgcn_s_setprio(1);
    #pragma unroll
    for (int kh=0;kh<2;kh++){
      const int sk = kh ? sA1 : sA0;
      #pragma unroll
      for (int fm=0;fm<4;fm++) af[kh][fm] = *(const short8*)&sc[abase + fm*1024 + sk];
      #pragma unroll
      for (int fn=0;fn<4;fn++){
        b0f[kh][fn] = *(const short8*)&sc[bbase + fn*1024 + sk];
        if (NB==2) b1f[kh][fn] = *(const short8*)&sc[8192 + bbase + fn*1024 + sk];
      }
    }
    #pragma unroll
    for (int kh=0;kh<2;kh++){
      #pragma unroll
      for (int fm=0;fm<4;fm++){
        #pragma unroll
        for (int fn=0;fn<4;fn++){
          acc0[fm][fn] = __builtin_amdgcn_mfma_f32_16x16x32_bf16(af[kh][fm], b0f[kh][fn], acc0[fm][fn],0,0,0);
          if (NB==2)
            acc1[fm][fn] = __builtin_amdgcn_mfma_f32_16x16x32_bf16(af[kh][fm], b1f[kh][fn], acc1[fm][fn],0,0,0);
        }
      }
    }
    __builtin_amdgcn_s_setprio(0);

    asm volatile("s_waitcnt lgkmcnt(0)" ::: "memory");
    BAR_FENCE;                                 // BAR1

    if (t+2 < nt){
      const size_t kt2 = (size_t)(t+2)*64;
      #pragma unroll
      for (int i=0;i<4;i++) gload16(ap[i] + kt2, &sn[(tid+512*i)*8]);
      SB0;
      asm volatile("s_waitcnt vmcnt(4)" ::: "memory");  // retire A(t+1); A(t+2) in flight
    } else if (t+1 < nt){
      asm volatile("s_waitcnt vmcnt(0)" ::: "memory");
    }
    BAR_FENCE;                                 // BAR2
  }

  // epilogue
  #pragma unroll
  for (int fm=0;fm<4;fm++){
    #pragma unroll
    for (int j=0;j<4;j++){
      int grow = wm*64 + fm*16 + lgrp*4 + j;
      if (row0+grow < cnt){
        int p = off + row0 + grow;
        u16* hrow = Hout + (size_t)p*N;
        #pragma unroll
        for (int fn=0;fn<4;fn++){
          int col = n0 + wn*64 + fn*16 + lrow;
          if (EPI==0){
            float g = acc0[fm][fn][j], u = acc1[fm][fn][j];
            hrow[col] = f2bf(g*u/(1.f+expf(-g)));
          } else {
            hrow[col] = f2bf(acc0[fm][fn][j]);
          }
        }
      }
    }
  }
}

// ---------------- combine ----------------
__global__ __launch_bounds__(256) void combine_kernel(const u16* __restrict__ pairbuf,
                                                      const int* __restrict__ pos,
                                                      const float* __restrict__ topk_w,
                                                      float* __restrict__ out){
  const int t = blockIdx.x;
  const int c = threadIdx.x*8;
  float acc[8] = {};
  #pragma unroll
  for (int k=0;k<TOPK;k++){
    int p = pos[t*TOPK+k];
    float w = topk_w[t*TOPK+k];
    uint4 v = *(const uint4*)&pairbuf[(size_t)p*HDIM + c];
    unsigned int ws_[4] = {v.x,v.y,v.z,v.w};
    #pragma unroll
    for (int j=0;j<4;j++){
      acc[2*j]   += w*bf2f(ws_[j]&0xffffu);
      acc[2*j+1] += w*bf2f(ws_[j]>>16);
    }
  }
  float4 o0 = {acc[0],acc[1],acc[2],acc[3]};
  float4 o1 = {acc[4],acc[5],acc[6],acc[7]};
  float* orow = out + (size_t)t*HDIM + c;
  *(float4*)orow = o0;
  *(float4*)(orow+4) = o1;
}

extern "C" void kernel_launch(void* const* d_in, const int* in_sizes, int n_in,
                              void* d_out, int out_size, void* d_ws, size_t ws_size,
                              hipStream_t stream) {
  const float* x  = (const float*)d_in[0];
  const float* gw = (const float*)d_in[1];
  const float* wg = (const float*)d_in[2];
  const float* wu = (const float*)d_in[3];
  const float* wd = (const float*)d_in[4];
  float* out = (float*)d_out;

  char* p = (char*)d_ws;
  u16* xb      = (u16*)p; p += (size_t)T_TOK*HDIM*2;   // 16.8 MB
  u16* hbuf    = (u16*)p; p += (size_t)NPAIR*MDIM*2;   // 69.2 MB
  u16* pairbuf = (u16*)p; p += (size_t)NPAIR*HDIM*2;   // 100.7 MB
  int*   topk_idx   = (int*)p;   p += NPAIR*4;
  float* topk_w     = (float*)p; p += NPAIR*4;
  int*   pair_token = (int*)p;   p += NPAIR*4;
  int*   pos        = (int*)p;   p += NPAIR*4;
  int*   counts     = (int*)p;   p += 128;
  int*   offsets    = (int*)p;   p += 128;
  int*   cursor     = (int*)p;   p += 128;

  hipMemsetAsync(counts, 0, 128, stream);
  cvt_kernel<<<T_TOK*HDIM/8/256, 256, 0, stream>>>(x, xb, T_TOK*HDIM/8);
  gate_kernel<<<T_TOK/4, 256, 0, stream>>>(x, gw, topk_idx, topk_w, counts);
  scan_kernel<<<1, 64, 0, stream>>>(counts, offsets, cursor);
  fill_kernel<<<T_TOK/256, 256, 0, stream>>>(topk_idx, topk_w, offsets, cursor, pair_token, pos);

  // stage 1: h = silu(x@wg) * (x@wu) — B = fp32 weights converted in-kernel by producer waves
  {
    int ntile = 8*(MDIM/128)*NEXP;   // 2464
    gemm10<2,true,0,(MDIM/128)><<<ntile, 768, 131072, stream>>>(
        xb, wg, wu, hbuf, counts, offsets, pair_token, HDIM, MDIM, ntile/8);
  }

  // stage 2: pairbuf = h @ wd — B = fp32 wd converted in-kernel
  {
    int ntile = 8*(HDIM/128)*NEXP;   // 3584
    gemm10<1,false,1,(HDIM/128)><<<ntile, 768, 98304, stream>>>(
        hbuf, wd, nullptr, pairbuf, counts, offsets, pair_token, MDIM, HDIM, ntile/8);
  }

  combine_kernel<<<T_TOK, 256, 0, stream>>>(pairbuf, pos, topk_w, out);
}